// Round 12
// baseline (12725.261 us; speedup 1.0000x reference)
//
#include <hip/hip_runtime.h>
#include <stdint.h>

// ---------------------------------------------------------------------------
// SimpleRNN: bidirectional LSTM encoder (S=256) + autoregressive decoder (T=128)
// B=128, D=256, H=1024. Persistent kernels, fence-free flag grid barriers.
// R12: geometry 128rows' x 32batches per WG (h duplication halved, 64->32
// MB/step). ALL staging via global_load_lds: Wih/x staged as raw f32 (cvt at
// read, P1 chunks 0..3 only), Whh/h/inp from bf16 planes. Unified 20-chunk
// loop: W ring depth-2, act/h ring depth-9, counted vmcnt, prefetch of W+x
// under the barrier spin. 3-term split-bf16 MFMA, f32 accum/gates.
// ---------------------------------------------------------------------------

typedef __attribute__((ext_vector_type(8))) short bfx8;
typedef __attribute__((ext_vector_type(4))) float f32x4;
typedef __attribute__((ext_vector_type(4))) unsigned short u16x4;
typedef unsigned short ushort_t;
typedef unsigned long long u64;

#define NWG 256
#define MFMA(a,b,c) __builtin_amdgcn_mfma_f32_16x16x32_bf16((a),(b),(c),0,0,0)
#define WAITVM(N) { asm volatile("s_waitcnt vmcnt(" #N ")" ::: "memory"); __builtin_amdgcn_sched_barrier(0); }
#define WAITLG(N) { asm volatile("s_waitcnt lgkmcnt(" #N ")" ::: "memory"); __builtin_amdgcn_sched_barrier(0); }
#define SBAR()    { __builtin_amdgcn_s_barrier(); __builtin_amdgcn_sched_barrier(0); }

__device__ __forceinline__ unsigned short f2bf(float f){
  unsigned u = __float_as_uint(f);
  u += 0x7FFFu + ((u >> 16) & 1u);          // round-to-nearest-even
  return (unsigned short)(u >> 16);
}
__device__ __forceinline__ float bf2f(unsigned short h){
  return __uint_as_float(((unsigned)h) << 16);
}
__device__ __forceinline__ float sigm(float x){ return 1.f/(1.f + __expf(-x)); }
__device__ __forceinline__ float tanh_(float x){ return 1.f - 2.f/(__expf(2.f*x) + 1.f); }

// plain (L1+L2 cached) async global->LDS: immutable data
__device__ __forceinline__ void stage16(const void* g, void* l){
  __builtin_amdgcn_global_load_lds((const __attribute__((address_space(1))) void*)g,
                                   (__attribute__((address_space(3))) void*)l,
                                   16, 0, 0);
}
// agent-coherent (SC0|SC1, L3-served): mutable cross-XCD data
__device__ __forceinline__ void stage16c(const void* g, void* l){
  __builtin_amdgcn_global_load_lds((const __attribute__((address_space(1))) void*)g,
                                   (__attribute__((address_space(3))) void*)l,
                                   16, 0, 0x11);
}
__device__ __forceinline__ void sth2(ushort_t* p, unsigned short v){
  __hip_atomic_store(p, v, __ATOMIC_RELAXED, __HIP_MEMORY_SCOPE_AGENT);
}

// two f32x4 (8 consecutive f32) -> hi/lo bf16 planes
__device__ __forceinline__ void cvt2(const f32x4& a, const f32x4& b, bfx8& hi, bfx8& lo){
#pragma unroll
  for (int j = 0; j < 4; ++j){
    unsigned short h0 = f2bf(a[j]);
    unsigned short h1 = f2bf(b[j]);
    hi[j]   = (short)h0; lo[j]   = (short)f2bf(a[j] - bf2f(h0));
    hi[4+j] = (short)h1; lo[4+j] = (short)f2bf(b[j] - bf2f(h1));
  }
}

// ---------------------------------------------------------------------------
// Staging descriptor: per-thread source bases + dest offsets, built once.
// W slot (16384 us): c<4 -> [128r][64k] f32 (row-split by wave 0/1);
//                    c>=4 -> hi plane @0, lo @8192 (plane-split by wave 0/1).
// act slot (4096 us): c<4 ENC -> [32r][64k] f32; DEC -> inp hi@0/lo@2048;
//                     c>=4 -> h hi@0/lo@2048. (wave2/3 split rows or planes.)
// ---------------------------------------------------------------------------
template<int ENC>
struct Stg {
  const float*    wih;    // f32 Wih (this dir), gate-interleave via addressing
  const ushort_t* whhb;   // per-thread Whh plane base (plane by wv)
  const float*    xb;     // ENC: per-thread x base (no tt offset)
  const ushort_t* ipb;    // DEC: per-thread inp plane base
  const ushort_t* hb;     // per-thread h plane base (+dir, no parity offset)
  int wdst, adst, r0;
  int lane, wv;

  __device__ void issue_w(int c, ushort_t* LDS) const {    // waves 0/1
    if (wv >= 2) return;
    ushort_t* d = LDS + (c & 1)*16384 + wdst;
    if (c < 4){
#pragma unroll
      for (int j = 0; j < 16; ++j){
        const int rp_ = r0 + (wv & 1)*64 + j*4 + (lane >> 4);
        const int srcrow = ((rp_ & 3) << 10) + (rp_ >> 2);
        stage16(wih + (size_t)srcrow*256 + (lane & 15)*4 + c*64, d + j*512);
      }
    } else {
#pragma unroll
      for (int j = 0; j < 16; ++j)
        stage16(whhb + j*8192 + (c - 4)*64, d + j*512);
    }
  }
  __device__ void issue_a(int c, int slot, ushort_t* LDS,
                          int xoff, unsigned hoff) const {  // waves 2/3
    if (wv < 2) return;
    ushort_t* d = LDS + 32768 + slot*4096 + adst;
    if (c < 4){
      if (ENC){
#pragma unroll
        for (int j = 0; j < 4; ++j)
          stage16(xb + (size_t)j*262144 + xoff + c*64, d + j*512);
      } else {
#pragma unroll
        for (int j = 0; j < 4; ++j)
          stage16c(ipb + j*2048 + c*64, d + j*512);
      }
    } else {
#pragma unroll
      for (int j = 0; j < 4; ++j)
        stage16c(hb + (size_t)j*16384 + hoff + (c - 4)*64, d + j*512);
    }
  }
};

template<int ENC>
__device__ __forceinline__ Stg<ENC> make_stg(
    const float* Wih, const ushort_t* WhH, const ushort_t* WhL,
    const float* x, const ushort_t* inph, const ushort_t* inpl,
    const ushort_t* Hhd, const ushort_t* Hld,   // + dir*1024 already
    int r0, int b0)
{
  const int lane = threadIdx.x & 63;
  const int wv   = threadIdx.x >> 6;
  const int srw  = lane >> 3;
  const int sg   = (lane & 7) ^ srw;
  Stg<ENC> s;
  s.wih = Wih; s.r0 = r0; s.lane = lane; s.wv = wv;
  s.wdst = (wv & 1)*8192;
  s.adst = (wv == 3) ? 2048 : 0;
  s.whhb = ((wv == 1) ? WhL : WhH) + (size_t)(r0 + srw)*1024 + sg*8;
  if (ENC){
    s.xb  = x + (size_t)(b0 + ((wv == 3) ? 16 : 0) + (lane >> 4))*65536 + (lane & 15)*4;
    s.ipb = nullptr;
  } else {
    s.xb  = nullptr;
    s.ipb = ((wv == 3) ? inpl : inph) + (size_t)(b0 + srw)*256 + sg*8;
  }
  s.hb = ((wv == 3) ? Hld : Hhd) + (size_t)(b0 + srw)*2048 + sg*8;
  return s;
}

// ---------------------------------------------------------------------------
// Plain fence-free grid barrier (wave0 scans).
// ---------------------------------------------------------------------------
__device__ __forceinline__ void bar(unsigned* flags, int nflags, int me, unsigned gen){
  __syncthreads();
  if (threadIdx.x == 0)
    __hip_atomic_store(&flags[me], gen, __ATOMIC_RELAXED, __HIP_MEMORY_SCOPE_AGENT);
  if (threadIdx.x < 64){
    const int l = threadIdx.x;
    for (;;){
      unsigned mn = 0xFFFFFFFFu;
      for (int o = l; o < nflags; o += 64){
        unsigned v = __hip_atomic_load(&flags[o], __ATOMIC_RELAXED, __HIP_MEMORY_SCOPE_AGENT);
        mn = mn < v ? mn : v;
      }
      if (__all((int)(mn >= gen))) break;
      __builtin_amdgcn_s_sleep(1);
    }
  }
  __syncthreads();
}

// ---------------------------------------------------------------------------
// Prefetching barrier: after entry s_barrier, waves 0/1 issue next step's W
// chunks 0,1; ENC waves 2/3 issue next step's x chunks 0..3 (immutable data
// only — h/inp are written by OTHER WGs and must wait for the spin).
// ---------------------------------------------------------------------------
template<int ENC>
__device__ __forceinline__ void bar_pf(unsigned* flags, int nflags, int me,
                                       unsigned gen, const Stg<ENC>& sg_,
                                       ushort_t* LDS, bool pf, int xoffn){
  WAITLG(0); WAITVM(0);
  SBAR();
  if (pf){
    if ((threadIdx.x >> 6) < 2){
      sg_.issue_w(0, LDS); sg_.issue_w(1, LDS);
    } else if (ENC){
#pragma unroll
      for (int c = 0; c < 4; ++c) sg_.issue_a(c, c, LDS, xoffn, 0);
    }
  }
  if (threadIdx.x == 192)
    __hip_atomic_store(&flags[me], gen, __ATOMIC_RELAXED, __HIP_MEMORY_SCOPE_AGENT);
  if ((threadIdx.x >> 6) == 3){
    const int l = threadIdx.x & 63;
    for (;;){
      unsigned mn = 0xFFFFFFFFu;
      for (int o = l; o < nflags; o += 64){
        unsigned v = __hip_atomic_load(&flags[o], __ATOMIC_RELAXED, __HIP_MEMORY_SCOPE_AGENT);
        mn = mn < v ? mn : v;
      }
      if (__all((int)(mn >= gen))) break;
      __builtin_amdgcn_s_sleep(1);
    }
  }
  SBAR();
}

struct Frags { bfx8 awh0, awh1, awl0, awl1, bh0, bh1, bl0, bl1; };

// ---------------------------------------------------------------------------
// One LSTM cell step: WG = 128 gate-interleaved rows' (32 neurons) x 32
// batches. Unified 20-chunk loop; chunks 0..3 read f32 (cvt at read);
// chunks 4..19 read bf16 planes (swizzled, conflict-free).
// ---------------------------------------------------------------------------
template<int ENC>
__device__ __forceinline__ void cell_step(
    const Stg<ENC>& sg_, const float* __restrict__ bias,
    ushort_t* __restrict__ outh, ushort_t* __restrict__ outl,
    float (&creg)[2][2], unsigned hoff,
    int n0, int b0, ushort_t* LDS)
{
  const int lane = threadIdx.x & 63;
  const int wv   = threadIdx.x >> 6;
  const int cb   = lane >> 4;
  const int fr   = lane & 15;
  const int sx   = fr & 7;
  const int rwa0 = wv*32 + fr, rwa1 = rwa0 + 16;   // W rows (0..127)
  const int rwb0 = fr, rwb1 = fr + 16;             // act rows (0..31)

  // ---- entry prologue (after grid barrier: h/inp of this step are final) ----
  if (!ENC){
#pragma unroll
    for (int c = 0; c < 4; ++c) sg_.issue_a(c, c, LDS, 0, hoff);
  }
#pragma unroll
  for (int c = 4; c < 9; ++c) sg_.issue_a(c, c, LDS, 0, hoff);

  f32x4 acc[2][2] = {};
  auto rdf = [&](const ushort_t* wb, const ushort_t* ab, int ks, Frags& f){
    const int ga = (((ks << 2) + cb) ^ sx) << 3;
    f.awh0 = *(const bfx8*)(wb +        rwa0*64 + ga);
    f.awh1 = *(const bfx8*)(wb +        rwa1*64 + ga);
    f.awl0 = *(const bfx8*)(wb + 8192 + rwa0*64 + ga);
    f.awl1 = *(const bfx8*)(wb + 8192 + rwa1*64 + ga);
    f.bh0  = *(const bfx8*)(ab +        rwb0*64 + ga);
    f.bh1  = *(const bfx8*)(ab +        rwb1*64 + ga);
    f.bl0  = *(const bfx8*)(ab + 2048 + rwb0*64 + ga);
    f.bl1  = *(const bfx8*)(ab + 2048 + rwb1*64 + ga);
  };
  auto mm12 = [&](const Frags& f){
    acc[0][0] = MFMA(f.awh0, f.bh0, acc[0][0]);
    acc[0][0] = MFMA(f.awh0, f.bl0, acc[0][0]);
    acc[0][0] = MFMA(f.awl0, f.bh0, acc[0][0]);
    acc[0][1] = MFMA(f.awh0, f.bh1, acc[0][1]);
    acc[0][1] = MFMA(f.awh0, f.bl1, acc[0][1]);
    acc[0][1] = MFMA(f.awl0, f.bh1, acc[0][1]);
    acc[1][0] = MFMA(f.awh1, f.bh0, acc[1][0]);
    acc[1][0] = MFMA(f.awh1, f.bl0, acc[1][0]);
    acc[1][0] = MFMA(f.awl1, f.bh0, acc[1][0]);
    acc[1][1] = MFMA(f.awh1, f.bh1, acc[1][1]);
    acc[1][1] = MFMA(f.awh1, f.bl1, acc[1][1]);
    acc[1][1] = MFMA(f.awl1, f.bh1, acc[1][1]);
  };

  int as = 0;                                // act slot = chunk % 9
  for (int i = 0; i < 20; ++i){
    if (wv < 2){
      if (i <= 18)      { WAITVM(16); }
      else              { WAITVM(0); }
    } else {
      if      (i <= 11) { WAITVM(32); }
      else if (i == 12) { WAITVM(28); }
      else if (i == 13) { WAITVM(24); }
      else if (i == 14) { WAITVM(20); }
      else if (i == 15) { WAITVM(16); }
      else if (i == 16) { WAITVM(12); }
      else if (i == 17) { WAITVM(8); }
      else if (i == 18) { WAITVM(4); }
      else              { WAITVM(0); }
    }
    SBAR();                                  // chunk i staged by all waves
    const ushort_t* wb = LDS + (i & 1)*16384;
    const ushort_t* ab = LDS + 32768 + as*4096;

    if (i < 4){
      // ---- P1 variant: W f32 (+ ENC act f32) with cvt at read ----
      const float* wf = (const float*)wb;
      const int ka0 = cb*8, ka1 = (4 + cb)*8;
      f32x4 w0a, w0b, w1a, w1b, w2a, w2b, w3a, w3b;
      f32x4 x0a, x0b, x1a, x1b, x2a, x2b, x3a, x3b;
      bfx8 dh0, dl0, dh1, dl1, dh2, dl2, dh3, dl3;
      // f0 reads (8)
      w0a = *(const f32x4*)(wf + rwa0*64 + ka0);
      w0b = *(const f32x4*)(wf + rwa0*64 + ka0 + 4);
      w1a = *(const f32x4*)(wf + rwa1*64 + ka0);
      w1b = *(const f32x4*)(wf + rwa1*64 + ka0 + 4);
      if (ENC){
        const float* af = (const float*)ab;
        x0a = *(const f32x4*)(af + rwb0*64 + ka0);
        x0b = *(const f32x4*)(af + rwb0*64 + ka0 + 4);
        x1a = *(const f32x4*)(af + rwb1*64 + ka0);
        x1b = *(const f32x4*)(af + rwb1*64 + ka0 + 4);
      } else {
        const int ga0 = (cb ^ sx) << 3;
        dh0 = *(const bfx8*)(ab +        rwb0*64 + ga0);
        dl0 = *(const bfx8*)(ab + 2048 + rwb0*64 + ga0);
        dh1 = *(const bfx8*)(ab +        rwb1*64 + ga0);
        dl1 = *(const bfx8*)(ab + 2048 + rwb1*64 + ga0);
      }
      // f1 reads (8)
      w2a = *(const f32x4*)(wf + rwa0*64 + ka1);
      w2b = *(const f32x4*)(wf + rwa0*64 + ka1 + 4);
      w3a = *(const f32x4*)(wf + rwa1*64 + ka1);
      w3b = *(const f32x4*)(wf + rwa1*64 + ka1 + 4);
      if (ENC){
        const float* af = (const float*)ab;
        x2a = *(const f32x4*)(af + rwb0*64 + ka1);
        x2b = *(const f32x4*)(af + rwb0*64 + ka1 + 4);
        x3a = *(const f32x4*)(af + rwb1*64 + ka1);
        x3b = *(const f32x4*)(af + rwb1*64 + ka1 + 4);
      } else {
        const int ga1 = ((4 + cb) ^ sx) << 3;
        dh2 = *(const bfx8*)(ab +        rwb0*64 + ga1);
        dl2 = *(const bfx8*)(ab + 2048 + rwb0*64 + ga1);
        dh3 = *(const bfx8*)(ab +        rwb1*64 + ga1);
        dl3 = *(const bfx8*)(ab + 2048 + rwb1*64 + ga1);
      }
      WAITLG(8);
      Frags f0;
      cvt2(w0a, w0b, f0.awh0, f0.awl0);
      cvt2(w1a, w1b, f0.awh1, f0.awl1);
      if (ENC){ cvt2(x0a, x0b, f0.bh0, f0.bl0); cvt2(x1a, x1b, f0.bh1, f0.bl1); }
      else    { f0.bh0 = dh0; f0.bl0 = dl0; f0.bh1 = dh1; f0.bl1 = dl1; }
      mm12(f0);
      WAITLG(0); SBAR();
      if (wv < 2) sg_.issue_w(i + 2, LDS);
      else        sg_.issue_a(i + 9, as, LDS, 0, hoff);
      Frags f1;
      cvt2(w2a, w2b, f1.awh0, f1.awl0);
      cvt2(w3a, w3b, f1.awh1, f1.awl1);
      if (ENC){ cvt2(x2a, x2b, f1.bh0, f1.bl0); cvt2(x3a, x3b, f1.bh1, f1.bl1); }
      else    { f1.bh0 = dh2; f1.bl0 = dl2; f1.bh1 = dh3; f1.bl1 = dl3; }
      mm12(f1);
    } else {
      Frags f0, f1;
      rdf(wb, ab, 0, f0);
      rdf(wb, ab, 1, f1);
      WAITLG(8);
      mm12(f0);
      WAITLG(0); SBAR();
      if (wv < 2){ if (i <= 17) sg_.issue_w(i + 2, LDS); }
      else       { if (i <= 10) sg_.issue_a(i + 9, as, LDS, 0, hoff); }
      mm12(f1);
    }
    as = (as == 8) ? 0 : as + 1;
  }

  // ---- epilogue: gates -> c (regs), h -> global hi/lo planes (coherent) ----
#pragma unroll
  for (int m = 0; m < 2; ++m){
    const int n = n0 + wv*8 + m*4 + cb;
    const float bi_ = bias[n];
    const float bf_ = bias[1024 + n];
    const float bg_ = bias[2048 + n];
    const float bo_ = bias[3072 + n];
#pragma unroll
    for (int nb = 0; nb < 2; ++nb){
      const int b = b0 + nb*16 + fr;
      float gi = acc[m][nb][0] + bi_;
      float gf = acc[m][nb][1] + bf_;
      float gg = acc[m][nb][2] + bg_;
      float go = acc[m][nb][3] + bo_;
      float c_new = sigm(gf)*creg[m][nb] + sigm(gi)*tanh_(gg);
      float h_new = sigm(go)*tanh_(c_new);
      creg[m][nb] = c_new;
      unsigned short hi = f2bf(h_new);
      sth2(&outh[(size_t)b*2048 + n], hi);
      sth2(&outl[(size_t)b*2048 + n], f2bf(h_new - bf2f(hi)));
    }
  }
}

// ---------------------------------------------------------------------------
// Decoder MLP (unchanged from R11): 32 WGs, 32d x 32b tile; K=2048 over 4
// waves, wave-private depth-4 ring (slot 4096 us); LDS combine.
// ---------------------------------------------------------------------------
__device__ __forceinline__ void mlp32(
    const ushort_t* __restrict__ hch, const ushort_t* __restrict__ hcl,
    const ushort_t* __restrict__ mWh, const ushort_t* __restrict__ mWl,
    const float* __restrict__ mb, float* __restrict__ dout,
    ushort_t* __restrict__ inph, ushort_t* __restrict__ inpl,
    int wg, int t, ushort_t* LDS)
{
  const int tid = threadIdx.x, lane = tid & 63, wv = tid >> 6;
  const int d0 = (wg >> 2)*32, b0 = (wg & 3)*32;
  const int kb = wv*512;
  const int srw2 = lane >> 2;
  const int pg   = lane & 3;

  const ushort_t* base[4] = { mWh, mWl, hch, hcl };
  const int rb0[4] = { d0, d0, b0, b0 };
  const ushort_t* sp[8];
#pragma unroll
  for (int j = 0; j < 8; ++j){
    const int p = j >> 1, sub = j & 1;
    const int rl = sub*16 + srw2;
    const int sr = (rl ^ (rl >> 2)) & 3;
    sp[j] = base[p] + (size_t)(rb0[p] + rl)*2048 + kb + ((pg ^ sr)*8);
  }
  ushort_t* lb[4];
#pragma unroll
  for (int s = 0; s < 4; ++s)
    lb[s] = LDS + 8192 + wv*16384 + s*4096;

  auto MISSUE = [&](int c){
    ushort_t* B = lb[c & 3];
    const int ko = c*32;
#pragma unroll
    for (int j = 0; j < 8; ++j){
      const int p = j >> 1, sub = j & 1;
      if (p < 2) stage16 (sp[j] + ko, B + p*1024 + sub*512 + lane*8);
      else       stage16c(sp[j] + ko, B + p*1024 + sub*512 + lane*8);
    }
  };
  MISSUE(0); MISSUE(1); MISSUE(2); MISSUE(3);

  f32x4 acc[2][2] = {};
  const int lg = lane >> 4;
  for (int c = 0; c < 16; ++c){
    if      (c <= 12) { WAITVM(24); }
    else if (c == 13) { WAITVM(16); }
    else if (c == 14) { WAITVM(8); }
    else              { WAITVM(0); }
    const ushort_t* B = lb[c & 3];
    bfx8 wf[2][2], af[2][2];
#pragma unroll
    for (int m = 0; m < 2; ++m){
      const int rl = m*16 + (lane & 15);
      const int sr = (rl ^ (rl >> 2)) & 3;
      const int off = rl*32 + ((lg ^ sr)*8);
      wf[0][m] = *(const bfx8*)(B + off);
      wf[1][m] = *(const bfx8*)(B + 1024 + off);
      af[0][m] = *(const bfx8*)(B + 2048 + off);
      af[1][m] = *(const bfx8*)(B + 3072 + off);
    }
    WAITLG(0);
    if (c < 12) MISSUE(c + 4);
#pragma unroll
    for (int m = 0; m < 2; ++m)
#pragma unroll
      for (int n = 0; n < 2; ++n){
        acc[m][n] = MFMA(wf[0][m], af[0][n], acc[m][n]);
        acc[m][n] = MFMA(wf[0][m], af[1][n], acc[m][n]);
        acc[m][n] = MFMA(wf[1][m], af[0][n], acc[m][n]);
      }
  }

  float* PL = (float*)LDS;
#pragma unroll
  for (int m = 0; m < 2; ++m)
#pragma unroll
    for (int n = 0; n < 2; ++n)
#pragma unroll
      for (int r = 0; r < 4; ++r)
        PL[wv*1024 + (m*2 + n)*256 + r*64 + lane] = acc[m][n][r];
  __syncthreads();
  for (int o = tid; o < 1024; o += 256){
    float s = PL[o] + PL[1024 + o] + PL[2048 + o] + PL[3072 + o];
    const int m = o >> 9, n = (o >> 8) & 1, r = (o >> 6) & 3, l = o & 63;
    const int d = d0 + m*16 + (l >> 4)*4 + r;
    const int b = b0 + n*16 + (l & 15);
    s += mb[d];
    dout[((size_t)b*128 + t)*256 + d] = s;
    const unsigned short hv = f2bf(s);
    sth2(&inph[(size_t)b*256 + d], hv);
    sth2(&inpl[(size_t)b*256 + d], f2bf(s - bf2f(hv)));
  }
}

// ---------------------------------------------------------------------------
// WG -> (dir, rowgroup, b-quarter). 4 quarters of a rowgroup share an XCD
// (round-robin assumption is a perf heuristic only).
// ---------------------------------------------------------------------------
__device__ __forceinline__ void wg_decode(int wg, int& dir, int& r0, int& n0,
                                          int& b0, int& me){
  const int slot = wg & 7;
  const int rest = wg >> 3;
  const int q    = rest & 3;
  const int rgd  = slot | ((rest >> 2) << 3);        // 0..63
  dir = rgd >> 5;
  const int rg = rgd & 31;
  r0 = rg * 128; n0 = rg * 32; b0 = q * 32;
  me = ((rgd & 31) << 2) | q;                        // 0..127 within dir
}

__global__ void __launch_bounds__(256) rnn_enc_kernel(
    const float* __restrict__ Wih_f, const float* __restrict__ b_f,
    const float* __restrict__ Wih_b, const float* __restrict__ b_b,
    const ushort_t* __restrict__ WhhH, const ushort_t* __restrict__ WhhL,
    const float* __restrict__ x,
    ushort_t* __restrict__ Hh, ushort_t* __restrict__ Hl,
    float* __restrict__ C, unsigned* flagsE)
{
  extern __shared__ ushort_t LDS[];
  int dir, r0, n0, b0, me;
  wg_decode(blockIdx.x, dir, r0, n0, b0, me);
  const float* Wih = dir ? Wih_b : Wih_f;
  const float* bia = dir ? b_b : b_f;
  const ushort_t* WhH = WhhH + (size_t)dir*4096*1024;
  const ushort_t* WhL = WhhL + (size_t)dir*4096*1024;
  unsigned* fl = flagsE + dir*128;
  const Stg<1> sg_ = make_stg<1>(Wih, WhH, WhL, x, nullptr, nullptr,
                                 Hh + dir*1024, Hl + dir*1024, r0, b0);

  float creg[2][2] = {{0.f, 0.f}, {0.f, 0.f}};
  // t=0 prologue: W chunks 0,1 + x chunks 0..3
  {
    const int wv = threadIdx.x >> 6;
    const int xoff0 = (dir ? 255 : 0) * 256;
    if (wv < 2){ sg_.issue_w(0, LDS); sg_.issue_w(1, LDS); }
    else {
#pragma unroll
      for (int c = 0; c < 4; ++c) sg_.issue_a(c, c, LDS, xoff0, 0);
    }
  }
  for (int t = 0; t < 256; ++t){
    const int rp = t & 1;
    cell_step<1>(sg_, bia,
                 Hh + (size_t)(rp^1)*262144 + dir*1024,
                 Hl + (size_t)(rp^1)*262144 + dir*1024,
                 creg, (unsigned)rp*262144u, n0, b0, LDS);
    const bool pf = (t < 255);
    const int ttn = dir ? (255 - (t + 1)) : (t + 1);
    bar_pf<1>(fl, 128, me, (unsigned)(t + 1), sg_, LDS, pf, pf ? ttn*256 : 0);
  }
  // hand off c-state to decoder (cross-kernel boundary flushes)
  {
    const int lane = threadIdx.x & 63, wv = threadIdx.x >> 6;
    const int cb = lane >> 4, fr = lane & 15;
    float* Cst = C + (size_t)dir*1024*128;
#pragma unroll
    for (int m = 0; m < 2; ++m)
#pragma unroll
      for (int nb = 0; nb < 2; ++nb){
        const int n = n0 + wv*8 + m*4 + cb;
        const int b = b0 + nb*16 + fr;
        Cst[n*128 + b] = creg[m][nb];
      }
  }
}

__global__ void __launch_bounds__(256) rnn_dec_kernel(
    const float* __restrict__ Wih_f, const float* __restrict__ b_f,
    const float* __restrict__ Wih_b, const float* __restrict__ b_b,
    const ushort_t* __restrict__ WhhH, const ushort_t* __restrict__ WhhL,
    const ushort_t* __restrict__ mWh, const ushort_t* __restrict__ mWl,
    const float* __restrict__ mb,
    ushort_t* __restrict__ Hh, ushort_t* __restrict__ Hl,
    float* __restrict__ C,
    ushort_t* __restrict__ inph, ushort_t* __restrict__ inpl,
    float* __restrict__ dout, unsigned* flagsD)
{
  extern __shared__ ushort_t LDS[];
  const int wg = blockIdx.x;
  int dir, r0, n0, b0, me;
  wg_decode(wg, dir, r0, n0, b0, me);
  const float* Wih = dir ? Wih_b : Wih_f;
  const float* bia = dir ? b_b : b_f;
  const ushort_t* WhH = WhhH + (size_t)dir*4096*1024;
  const ushort_t* WhL = WhhL + (size_t)dir*4096*1024;
  const Stg<0> sg_ = make_stg<0>(Wih, WhH, WhL, nullptr, inph, inpl,
                                 Hh + dir*1024, Hl + dir*1024, r0, b0);

  float creg[2][2];
  {
    const int lane = threadIdx.x & 63, wv = threadIdx.x >> 6;
    const int cb = lane >> 4, fr = lane & 15;
    const float* Cst = C + (size_t)dir*1024*128;
#pragma unroll
    for (int m = 0; m < 2; ++m)
#pragma unroll
      for (int nb = 0; nb < 2; ++nb){
        const int n = n0 + wv*8 + m*4 + cb;
        const int b = b0 + nb*16 + fr;
        creg[m][nb] = Cst[n*128 + b];
      }
  }
  if ((threadIdx.x >> 6) < 2){ sg_.issue_w(0, LDS); sg_.issue_w(1, LDS); }
  for (int t = 0; t < 128; ++t){
    const int rp = t & 1;
    cell_step<0>(sg_, bia,
                 Hh + (size_t)(rp^1)*262144 + dir*1024,
                 Hl + (size_t)(rp^1)*262144 + dir*1024,
                 creg, (unsigned)rp*262144u, n0, b0, LDS);
    bar(flagsD, 256, wg, (unsigned)(2*t + 1));
    if (wg < 32)
      mlp32(Hh + (size_t)(rp^1)*262144, Hl + (size_t)(rp^1)*262144,
            mWh, mWl, mb, dout, inph, inpl, wg, t, LDS);
    bar_pf<0>(flagsD, 256, wg, (unsigned)(2*t + 2), sg_, LDS, t < 127, 0);
  }
}

// ---------------------------------------------------------------------------
// Prep kernels
// ---------------------------------------------------------------------------
__global__ void k_wplanes(ushort_t* Hp, ushort_t* Lp,
                          const float* Whh_f, const float* Whh_b)
{
  const size_t N = 2ull*4096*1024;
  for (size_t i = (size_t)blockIdx.x*blockDim.x + threadIdx.x; i < N;
       i += (size_t)gridDim.x*blockDim.x){
    int dir = (int)(i >> 22);
    int r   = (int)((i >> 10) & 4095);
    int k   = (int)(i & 1023);
    int n = r >> 2, q = r & 3;
    const float* W = dir ? Whh_b : Whh_f;
    float v = W[(size_t)(q*1024 + n)*1024 + k];
    unsigned short h = f2bf(v);
    Hp[i] = h;
    Lp[i] = f2bf(v - bf2f(h));
  }
}

__global__ void k_init(ushort_t* Hh, ushort_t* Hl,
                       ushort_t* inph, ushort_t* inpl,
                       ushort_t* mWh, ushort_t* mWl,
                       const float* x, const float* mW, unsigned* cnt)
{
  const size_t N = 524288;
  for (size_t i = (size_t)blockIdx.x*blockDim.x + threadIdx.x; i < N;
       i += (size_t)gridDim.x*blockDim.x){
    Hh[i] = 0; Hl[i] = 0;
    float wv = mW[i];
    unsigned short wh = f2bf(wv);
    mWh[i] = wh;
    mWl[i] = f2bf(wv - bf2f(wh));
    if (i < 32768){
      int b = (int)(i >> 8), d = (int)(i & 255);
      float v = x[((size_t)b*256 + 255)*256 + d];        // x[:, 255, :]
      unsigned short hi = f2bf(v);
      inph[i] = hi;
      inpl[i] = f2bf(v - bf2f(hi));
    }
    if (i < 2048) cnt[i] = 0;
  }
}

// ---------------------------------------------------------------------------
extern "C" void kernel_launch(void* const* d_in, const int* in_sizes, int n_in,
                              void* d_out, int out_size, void* d_ws, size_t ws_size,
                              hipStream_t stream)
{
  (void)in_sizes; (void)n_in; (void)out_size; (void)ws_size;
  const float* x      = (const float*)d_in[0];
  const float* eWih_f = (const float*)d_in[2];
  const float* eWhh_f = (const float*)d_in[3];
  const float* eb_f   = (const float*)d_in[4];
  const float* eWih_b = (const float*)d_in[5];
  const float* eWhh_b = (const float*)d_in[6];
  const float* eb_b   = (const float*)d_in[7];
  const float* dWih_f = (const float*)d_in[8];
  const float* dWhh_f = (const float*)d_in[9];
  const float* db_f   = (const float*)d_in[10];
  const float* dWih_b = (const float*)d_in[11];
  const float* dWhh_b = (const float*)d_in[12];
  const float* db_b   = (const float*)d_in[13];
  const float* mW     = (const float*)d_in[14];
  const float* mb     = (const float*)d_in[15];

  char* p = (char*)d_ws;
  size_t off = 0;
  unsigned* cnt   = (unsigned*)(p + off);  off += 8192;
  ushort_t* WhhEh = (ushort_t*)(p + off);  off += 16777216;
  ushort_t* WhhEl = (ushort_t*)(p + off);  off += 16777216;
  ushort_t* WhhDh = (ushort_t*)(p + off);  off += 16777216;
  ushort_t* WhhDl = (ushort_t*)(p + off);  off += 16777216;
  ushort_t* mWh   = (ushort_t*)(p + off);  off += 1048576;
  ushort_t* mWl   = (ushort_t*)(p + off);  off += 1048576;
  ushort_t* Hh    = (ushort_t*)(p + off);  off += 1048576;
  ushort_t* Hl    = (ushort_t*)(p + off);  off += 1048576;
  float*    C     = (float*)(p + off);     off += 1048576;
  ushort_t* inph  = (ushort_t*)(p + off);  off += 65536;
  ushort_t* inpl  = (ushort_t*)(p + off);  off += 65536;

  unsigned* flagsD = cnt;              // 256
  unsigned* flagsE = cnt + 256;        // 2 x 128

  hipFuncSetAttribute(reinterpret_cast<const void*>(rnn_enc_kernel),
                      hipFuncAttributeMaxDynamicSharedMemorySize, 147456);
  hipFuncSetAttribute(reinterpret_cast<const void*>(rnn_dec_kernel),
                      hipFuncAttributeMaxDynamicSharedMemorySize, 147456);

  k_init   <<<512, 256, 0, stream>>>(Hh, Hl, inph, inpl, mWh, mWl, x, mW, cnt);
  k_wplanes<<<2048, 256, 0, stream>>>(WhhEh, WhhEl, eWhh_f, eWhh_b);
  k_wplanes<<<2048, 256, 0, stream>>>(WhhDh, WhhDl, dWhh_f, dWhh_b);

  rnn_enc_kernel<<<NWG, 256, 147456, stream>>>(eWih_f, eb_f, eWih_b, eb_b,
                                               WhhEh, WhhEl, x, Hh, Hl, C, flagsE);
  rnn_dec_kernel<<<NWG, 256, 147456, stream>>>(dWih_f, db_f, dWih_b, db_b,
                                               WhhDh, WhhDl, mWh, mWl, mb,
                                               Hh, Hl, C, inph, inpl,
                                               (float*)d_out, flagsD);
}

// Round 13
// 9899.575 us; speedup vs baseline: 1.2854x; 1.2854x over previous
//
#include <hip/hip_runtime.h>
#include <stdint.h>

// ---------------------------------------------------------------------------
// SimpleRNN: bidirectional LSTM encoder (S=256) + autoregressive decoder (T=128)
// B=128, D=256, H=1024. Persistent kernels, fence-free flag grid barriers.
// R13 = hybrid of proven-best halves:
//   encoder = R11 (deep h-ring depth-5, W ring depth-2, phase-1 VMEM-free,
//             W prefetched under barrier spin) -> 5.67 ms measured
//   decoder = R7  (cell ring depth-3, mlp_gemm 256-WG K-split + Part +
//             128-WG combine, 3 barriers/step) -> 4.03 ms measured
// 3-term split-bf16 MFMA (Wh*Ah + Wh*Al + Wl*Ah), f32 accum/gates.
// ---------------------------------------------------------------------------

typedef __attribute__((ext_vector_type(8))) short bfx8;
typedef __attribute__((ext_vector_type(4))) float f32x4;
typedef __attribute__((ext_vector_type(4))) unsigned short u16x4;
typedef unsigned short ushort_t;
typedef unsigned long long u64;

#define NWG 256
#define MFMA(a,b,c) __builtin_amdgcn_mfma_f32_16x16x32_bf16((a),(b),(c),0,0,0)
#define WAITVM(N) { asm volatile("s_waitcnt vmcnt(" #N ")" ::: "memory"); __builtin_amdgcn_sched_barrier(0); }
#define WAITLG(N) { asm volatile("s_waitcnt lgkmcnt(" #N ")" ::: "memory"); __builtin_amdgcn_sched_barrier(0); }
#define SBAR()    { __builtin_amdgcn_s_barrier(); __builtin_amdgcn_sched_barrier(0); }
#define SCHED0()  __builtin_amdgcn_sched_barrier(0)

__device__ __forceinline__ unsigned short f2bf(float f){
  unsigned u = __float_as_uint(f);
  u += 0x7FFFu + ((u >> 16) & 1u);          // round-to-nearest-even
  return (unsigned short)(u >> 16);
}
__device__ __forceinline__ float bf2f(unsigned short h){
  return __uint_as_float(((unsigned)h) << 16);
}
__device__ __forceinline__ float sigm(float x){ return 1.f/(1.f + __expf(-x)); }
__device__ __forceinline__ float tanh_(float x){ return 1.f - 2.f/(__expf(2.f*x) + 1.f); }

// plain (L1+L2 cached) async global->LDS: immutable weights
__device__ __forceinline__ void stage16(const void* g, void* l){
  __builtin_amdgcn_global_load_lds((const __attribute__((address_space(1))) void*)g,
                                   (__attribute__((address_space(3))) void*)l,
                                   16, 0, 0);
}
// agent-coherent (SC0|SC1 = 0x11, L3-served): mutable cross-XCD data
__device__ __forceinline__ void stage16c(const void* g, void* l){
  __builtin_amdgcn_global_load_lds((const __attribute__((address_space(1))) void*)g,
                                   (__attribute__((address_space(3))) void*)l,
                                   16, 0, 0x11);
}

// coherent 16B load (2 x u64 agent-relaxed atomics)
__device__ __forceinline__ bfx8 ld16c(const ushort_t* p){
  const u64* q = (const u64*)p;
  u64 a = __hip_atomic_load(q,     __ATOMIC_RELAXED, __HIP_MEMORY_SCOPE_AGENT);
  u64 b = __hip_atomic_load(q + 1, __ATOMIC_RELAXED, __HIP_MEMORY_SCOPE_AGENT);
  union { u64 u[2]; bfx8 v; } x; x.u[0] = a; x.u[1] = b; return x.v;
}
__device__ __forceinline__ void sth2(ushort_t* p, unsigned short v){
  __hip_atomic_store(p, v, __ATOMIC_RELAXED, __HIP_MEMORY_SCOPE_AGENT);
}

// two f32x4 (8 consecutive f32) -> hi/lo bf16 planes
__device__ __forceinline__ void cvt2(const f32x4& a, const f32x4& b, bfx8& hi, bfx8& lo){
#pragma unroll
  for (int j = 0; j < 4; ++j){
    unsigned short h0 = f2bf(a[j]);
    unsigned short h1 = f2bf(b[j]);
    hi[j]   = (short)h0; lo[j]   = (short)f2bf(a[j] - bf2f(h0));
    hi[4+j] = (short)h1; lo[4+j] = (short)f2bf(b[j] - bf2f(h1));
  }
}

// ---------------------------------------------------------------------------
// Plain fence-free grid barrier (wave0 scans).
// ---------------------------------------------------------------------------
__device__ __forceinline__ void bar(unsigned* flags, int nflags, int me, unsigned gen){
  __syncthreads();                       // drains vmcnt(0): all stores done
  if (threadIdx.x == 0)
    __hip_atomic_store(&flags[me], gen, __ATOMIC_RELAXED, __HIP_MEMORY_SCOPE_AGENT);
  if (threadIdx.x < 64){
    const int l = threadIdx.x;
    for (;;){
      unsigned mn = 0xFFFFFFFFu;
      for (int o = l; o < nflags; o += 64){
        unsigned v = __hip_atomic_load(&flags[o], __ATOMIC_RELAXED, __HIP_MEMORY_SCOPE_AGENT);
        mn = mn < v ? mn : v;
      }
      if (__all((int)(mn >= gen))) break;
      __builtin_amdgcn_s_sleep(1);
    }
  }
  __syncthreads();
}

// ---------------------------------------------------------------------------
// Prefetching barrier (encoder): waves 0/1 issue next step's W chunks 4,5
// into W ring slots 0/1 while wave3 stores the flag and spin-scans.
// ---------------------------------------------------------------------------
struct WPre {
  const ushort_t* pj[8];
  ushort_t* ldsb[2];
  bool active;                           // wv < 2
};
__device__ __forceinline__ void wpre_issue(const WPre& w){
  if (!w.active) return;
#pragma unroll
  for (int bp = 0; bp < 2; ++bp)
#pragma unroll
    for (int j = 0; j < 8; ++j)
      stage16(w.pj[j] + bp*64, w.ldsb[bp] + j*512);
}
__device__ __forceinline__ void bar_pf(unsigned* flags, int nflags, int me,
                                       unsigned gen, const WPre& w, bool pf){
  WAITLG(0); WAITVM(0);                  // own h-stores drained
  SBAR();                                // whole WG drained
  if (pf) wpre_issue(w);                 // waves 0/1: 16 W loads in flight
  if (threadIdx.x == 192)
    __hip_atomic_store(&flags[me], gen, __ATOMIC_RELAXED, __HIP_MEMORY_SCOPE_AGENT);
  if ((threadIdx.x >> 6) == 3){
    const int l = threadIdx.x & 63;
    for (;;){
      unsigned mn = 0xFFFFFFFFu;
      for (int o = l; o < nflags; o += 64){
        unsigned v = __hip_atomic_load(&flags[o], __ATOMIC_RELAXED, __HIP_MEMORY_SCOPE_AGENT);
        mn = mn < v ? mn : v;
      }
      if (__all((int)(mn >= gen))) break;
      __builtin_amdgcn_s_sleep(1);
    }
  }
  SBAR();
}

struct Frags { bfx8 awh0, awh1, awl0, awl1, bh0, bh1, bl0, bl1; };

// ===========================================================================
// ENCODER cell (R11): phase 1 VMEM-free (raws preloaded before 40-op h burst),
// phase 2 W ring depth-2 (@16384us), h ring depth-5 (@32768us).
// LDS total 73728 us = 144 KB.
// ===========================================================================
__device__ __forceinline__ void cell_enc(
    const float*    __restrict__ Wih,
    const ushort_t* __restrict__ WhH, const ushort_t* __restrict__ WhL,
    const float*    __restrict__ bias,
    const float*    __restrict__ xsl,   // x + tt*256 (row stride 65536)
    const ushort_t* __restrict__ hh, const ushort_t* __restrict__ hl,
    ushort_t* __restrict__ outh, ushort_t* __restrict__ outl,
    float (&creg)[2][2],
    int r0, int n0, int b0, ushort_t* LDS)
{
  const int tid  = threadIdx.x;
  const int lane = tid & 63;
  const int wv   = tid >> 6;
  const int wm   = wv >> 1, wn = wv & 1;
  const int lr   = tid >> 3;
  const int lc   = tid & 7;
  const int cb   = lane >> 4;
  const int fr   = lane & 15;
  const int sc8  = lc ^ (lr & 7);
  const int sx   = fr & 7;
  const int rwa0 = wm*32 + fr, rwa1 = rwa0 + 16;
  const int rwb0 = wn*32 + fr, rwb1 = rwb0 + 16;

  const int ra = r0 + lr, rb = ra + 32;
  const float* wih0 = Wih + (size_t)((ra & 3)*1024 + (ra >> 2))*256 + sc8*8;
  const float* wih1 = Wih + (size_t)((rb & 3)*1024 + (rb >> 2))*256 + sc8*8;
  const float* xs0 = xsl + (size_t)(b0 + lr)*65536 + sc8*8;
  const float* xs1 = xs0 + (size_t)32*65536;

  const ushort_t* sb; size_t sstr; int srow0;
  if      (wv == 0){ sb = WhH; sstr = 1024; srow0 = r0; }
  else if (wv == 1){ sb = WhL; sstr = 1024; srow0 = r0; }
  else if (wv == 2){ sb = hh;  sstr = 2048; srow0 = b0; }
  else             { sb = hl;  sstr = 2048; srow0 = b0; }
  const int srw = lane >> 3;
  const int sg  = (lane & 7) ^ srw;
  const ushort_t* pj[8];
#pragma unroll
  for (int j = 0; j < 8; ++j)
    pj[j] = sb + (size_t)(srow0 + j*8 + srw)*sstr + sg*8;

  auto ISSUE_W = [&](int c, int s){
    const int ko = (c - 4)*64;
    ushort_t* d = LDS + 16384 + s*8192 + (wv & 1)*4096;
#pragma unroll
    for (int j = 0; j < 8; ++j) stage16(pj[j] + ko, d + j*512);
  };
  auto ISSUE_H = [&](int c, int s){
    const int ko = (c - 4)*64;
    ushort_t* d = LDS + 32768 + s*8192 + (wv & 1)*4096;
#pragma unroll
    for (int j = 0; j < 8; ++j) stage16c(pj[j] + ko, d + j*512);
  };

  f32x4 acc[2][2] = {};
  auto rdf = [&](const ushort_t* wb, const ushort_t* ab, int ks, Frags& f){
    const int ga = (((ks << 2) + cb) ^ sx) << 3;
    f.awh0 = *(const bfx8*)(wb +        rwa0*64 + ga);
    f.awh1 = *(const bfx8*)(wb +        rwa1*64 + ga);
    f.awl0 = *(const bfx8*)(wb + 4096 + rwa0*64 + ga);
    f.awl1 = *(const bfx8*)(wb + 4096 + rwa1*64 + ga);
    f.bh0  = *(const bfx8*)(ab +        rwb0*64 + ga);
    f.bh1  = *(const bfx8*)(ab +        rwb1*64 + ga);
    f.bl0  = *(const bfx8*)(ab + 2048 + rwb0*64 + ga);
    f.bl1  = *(const bfx8*)(ab + 2048 + rwb1*64 + ga);
  };
  auto rdf3 = [&](const ushort_t* wb, const ushort_t* ab, int ks, Frags& f){
    const int ga = (((ks << 2) + cb) ^ sx) << 3;
    f.awh0 = *(const bfx8*)(wb +        rwa0*64 + ga);
    f.awh1 = *(const bfx8*)(wb +        rwa1*64 + ga);
    f.awl0 = *(const bfx8*)(wb + 4096 + rwa0*64 + ga);
    f.awl1 = *(const bfx8*)(wb + 4096 + rwa1*64 + ga);
    f.bh0  = *(const bfx8*)(ab +        rwb0*64 + ga);
    f.bh1  = *(const bfx8*)(ab +        rwb1*64 + ga);
    f.bl0  = *(const bfx8*)(ab + 4096 + rwb0*64 + ga);
    f.bl1  = *(const bfx8*)(ab + 4096 + rwb1*64 + ga);
  };
  auto mm12 = [&](const Frags& f){
    acc[0][0] = MFMA(f.awh0, f.bh0, acc[0][0]);
    acc[0][0] = MFMA(f.awh0, f.bl0, acc[0][0]);
    acc[0][0] = MFMA(f.awl0, f.bh0, acc[0][0]);
    acc[0][1] = MFMA(f.awh0, f.bh1, acc[0][1]);
    acc[0][1] = MFMA(f.awh0, f.bl1, acc[0][1]);
    acc[0][1] = MFMA(f.awl0, f.bh1, acc[0][1]);
    acc[1][0] = MFMA(f.awh1, f.bh0, acc[1][0]);
    acc[1][0] = MFMA(f.awh1, f.bl0, acc[1][0]);
    acc[1][0] = MFMA(f.awl1, f.bh0, acc[1][0]);
    acc[1][1] = MFMA(f.awh1, f.bh1, acc[1][1]);
    acc[1][1] = MFMA(f.awh1, f.bl1, acc[1][1]);
    acc[1][1] = MFMA(f.awl1, f.bh1, acc[1][1]);
  };
  (void)rdf3;

  // ---- phase-1 preload: ALL raws first (older than h burst) ----
  f32x4 rw[4][4], rx[4][4];
#pragma unroll
  for (int c = 0; c < 4; ++c){
    const int kc = c*64;
    rw[c][0] = *(const f32x4*)(wih0 + kc);  rw[c][1] = *(const f32x4*)(wih0 + kc + 4);
    rw[c][2] = *(const f32x4*)(wih1 + kc);  rw[c][3] = *(const f32x4*)(wih1 + kc + 4);
    rx[c][0] = *(const f32x4*)(xs0 + kc);   rx[c][1] = *(const f32x4*)(xs0 + kc + 4);
    rx[c][2] = *(const f32x4*)(xs1 + kc);   rx[c][3] = *(const f32x4*)(xs1 + kc + 4);
  }
  SCHED0();
  if (wv >= 2){
#pragma unroll
    for (int s = 0; s < 5; ++s) ISSUE_H(4 + s, s);
  }
  SCHED0();
  bfx8 swh[4][2], swl[4][2], sah[4][2], sal[4][2];
#pragma unroll
  for (int c = 0; c < 4; ++c){
    cvt2(rw[c][0], rw[c][1], swh[c][0], swl[c][0]);
    cvt2(rw[c][2], rw[c][3], swh[c][1], swl[c][1]);
    cvt2(rx[c][0], rx[c][1], sah[c][0], sal[c][0]);
    cvt2(rx[c][2], rx[c][3], sah[c][1], sal[c][1]);
  }

  // ---- phase 1: chunks 0..3 (VMEM-free) ----
#pragma unroll
  for (int c = 0; c < 4; ++c){
    *(bfx8*)(LDS +         lr    *64 + lc*8) = swh[c][0];
    *(bfx8*)(LDS +        (lr+32)*64 + lc*8) = swh[c][1];
    *(bfx8*)(LDS + 4096 +  lr    *64 + lc*8) = swl[c][0];
    *(bfx8*)(LDS + 4096 + (lr+32)*64 + lc*8) = swl[c][1];
    *(bfx8*)(LDS + 8192 +  lr    *64 + lc*8) = sah[c][0];
    *(bfx8*)(LDS + 8192 + (lr+32)*64 + lc*8) = sah[c][1];
    *(bfx8*)(LDS + 12288 + lr    *64 + lc*8) = sal[c][0];
    *(bfx8*)(LDS + 12288 +(lr+32)*64 + lc*8) = sal[c][1];
    WAITLG(0); SBAR();
    Frags f0, f1;
    { const int ga0 = ((cb) ^ sx) << 3, ga1 = ((4 + cb) ^ sx) << 3;
      f0.awh0 = *(const bfx8*)(LDS +        rwa0*64 + ga0);
      f0.awh1 = *(const bfx8*)(LDS +        rwa1*64 + ga0);
      f0.awl0 = *(const bfx8*)(LDS + 4096 + rwa0*64 + ga0);
      f0.awl1 = *(const bfx8*)(LDS + 4096 + rwa1*64 + ga0);
      f0.bh0  = *(const bfx8*)(LDS + 8192 + rwb0*64 + ga0);
      f0.bh1  = *(const bfx8*)(LDS + 8192 + rwb1*64 + ga0);
      f0.bl0  = *(const bfx8*)(LDS + 12288+ rwb0*64 + ga0);
      f0.bl1  = *(const bfx8*)(LDS + 12288+ rwb1*64 + ga0);
      f1.awh0 = *(const bfx8*)(LDS +        rwa0*64 + ga1);
      f1.awh1 = *(const bfx8*)(LDS +        rwa1*64 + ga1);
      f1.awl0 = *(const bfx8*)(LDS + 4096 + rwa0*64 + ga1);
      f1.awl1 = *(const bfx8*)(LDS + 4096 + rwa1*64 + ga1);
      f1.bh0  = *(const bfx8*)(LDS + 8192 + rwb0*64 + ga1);
      f1.bh1  = *(const bfx8*)(LDS + 8192 + rwb1*64 + ga1);
      f1.bl0  = *(const bfx8*)(LDS + 12288+ rwb0*64 + ga1);
      f1.bl1  = *(const bfx8*)(LDS + 12288+ rwb1*64 + ga1);
    }
    WAITLG(8);
    mm12(f0);
    WAITLG(0); SBAR();
    mm12(f1);
  }

  // ---- phase 2: chunks 4..19; W ring(2) @16384, h ring(5) @32768 ----
  int hcs = 0, his = 0;
  for (int i = 4; i <= 19; ++i){
    if (wv < 2){
      if (i <= 18) { WAITVM(8); } else { WAITVM(0); }
    } else {
      if      (i <= 15) { WAITVM(32); }
      else if (i == 16) { WAITVM(24); }
      else if (i == 17) { WAITVM(16); }
      else if (i == 18) { WAITVM(8); }
      else              { WAITVM(0); }
    }
    SBAR();
    const ushort_t* wb = LDS + 16384 + (i & 1)*8192;
    const ushort_t* ab = LDS + 32768 + hcs*8192;
    Frags f0, f1;
    { const int ga0 = ((cb) ^ sx) << 3, ga1 = ((4 + cb) ^ sx) << 3;
      f0.awh0 = *(const bfx8*)(wb +        rwa0*64 + ga0);
      f0.awh1 = *(const bfx8*)(wb +        rwa1*64 + ga0);
      f0.awl0 = *(const bfx8*)(wb + 4096 + rwa0*64 + ga0);
      f0.awl1 = *(const bfx8*)(wb + 4096 + rwa1*64 + ga0);
      f0.bh0  = *(const bfx8*)(ab +        rwb0*64 + ga0);
      f0.bh1  = *(const bfx8*)(ab +        rwb1*64 + ga0);
      f0.bl0  = *(const bfx8*)(ab + 4096 + rwb0*64 + ga0);
      f0.bl1  = *(const bfx8*)(ab + 4096 + rwb1*64 + ga0);
      f1.awh0 = *(const bfx8*)(wb +        rwa0*64 + ga1);
      f1.awh1 = *(const bfx8*)(wb +        rwa1*64 + ga1);
      f1.awl0 = *(const bfx8*)(wb + 4096 + rwa0*64 + ga1);
      f1.awl1 = *(const bfx8*)(wb + 4096 + rwa1*64 + ga1);
      f1.bh0  = *(const bfx8*)(ab +        rwb0*64 + ga1);
      f1.bh1  = *(const bfx8*)(ab +        rwb1*64 + ga1);
      f1.bl0  = *(const bfx8*)(ab + 4096 + rwb0*64 + ga1);
      f1.bl1  = *(const bfx8*)(ab + 4096 + rwb1*64 + ga1);
    }
    WAITLG(8);
    mm12(f0);
    WAITLG(0); SBAR();
    if (wv < 2){ if (i <= 17) ISSUE_W(i + 2, i & 1); }
    else       { if (i <= 14) ISSUE_H(i + 5, his); }
    mm12(f1);
    hcs = (hcs == 4) ? 0 : hcs + 1;
    his = (his == 4) ? 0 : his + 1;
  }

  // ---- epilogue ----
#pragma unroll
  for (int m = 0; m < 2; ++m){
    const int n = n0 + wm*8 + m*4 + cb;
    const float bi_ = bias[n];
    const float bf_ = bias[1024 + n];
    const float bg_ = bias[2048 + n];
    const float bo_ = bias[3072 + n];
#pragma unroll
    for (int nb = 0; nb < 2; ++nb){
      const int b = b0 + wn*32 + nb*16 + fr;
      float gi = acc[m][nb][0] + bi_;
      float gf = acc[m][nb][1] + bf_;
      float gg = acc[m][nb][2] + bg_;
      float go = acc[m][nb][3] + bo_;
      float c_new = sigm(gf)*creg[m][nb] + sigm(gi)*tanh_(gg);
      float h_new = sigm(go)*tanh_(c_new);
      creg[m][nb] = c_new;
      unsigned short hi = f2bf(h_new);
      sth2(&outh[(size_t)b*2048 + n], hi);
      sth2(&outl[(size_t)b*2048 + n], f2bf(h_new - bf2f(hi)));
    }
  }
}

// ===========================================================================
// DECODER cell (R7): ring depth-3 @16384+bp*16384, P1 register-staged.
// ===========================================================================
__device__ __forceinline__ void cell_dec(
    const float*    __restrict__ Wih,
    const ushort_t* __restrict__ WhH, const ushort_t* __restrict__ WhL,
    const float*    __restrict__ bias,
    const ushort_t* __restrict__ iph, const ushort_t* __restrict__ ipl,
    const ushort_t* __restrict__ hh,  const ushort_t* __restrict__ hl,
    ushort_t* __restrict__ outh, ushort_t* __restrict__ outl,
    float (&creg)[2][2],
    int r0, int n0, int b0, ushort_t* LDS)
{
  const int tid  = threadIdx.x;
  const int lane = tid & 63;
  const int wv   = tid >> 6;
  const int wm   = wv >> 1, wn = wv & 1;
  const int lr   = tid >> 3;
  const int lc   = tid & 7;
  const int cb   = lane >> 4;
  const int fr   = lane & 15;
  const int sc8  = lc ^ (lr & 7);
  const int sx   = fr & 7;
  const int rwa0 = wm*32 + fr, rwa1 = rwa0 + 16;
  const int rwb0 = wn*32 + fr, rwb1 = rwb0 + 16;

  const int ra = r0 + lr, rb = ra + 32;
  const float* wih0 = Wih + (size_t)((ra & 3)*1024 + (ra >> 2))*256 + sc8*8;
  const float* wih1 = Wih + (size_t)((rb & 3)*1024 + (rb >> 2))*256 + sc8*8;
  const ushort_t* ih0 = iph + (size_t)(b0 + lr)*256 + sc8*8;
  const ushort_t* ih1 = ih0 + 32*256;
  const ushort_t* il0 = ipl + (size_t)(b0 + lr)*256 + sc8*8;
  const ushort_t* il1 = il0 + 32*256;

  const ushort_t* sb; size_t sstr; int srow0;
  if      (wv == 0){ sb = WhH; sstr = 1024; srow0 = r0; }
  else if (wv == 1){ sb = WhL; sstr = 1024; srow0 = r0; }
  else if (wv == 2){ sb = hh;  sstr = 2048; srow0 = b0; }
  else             { sb = hl;  sstr = 2048; srow0 = b0; }
  const int srw = lane >> 3;
  const int sg  = (lane & 7) ^ srw;
  const ushort_t* pj[8];
#pragma unroll
  for (int j = 0; j < 8; ++j)
    pj[j] = sb + (size_t)(srow0 + j*8 + srw)*sstr + sg*8;
  ushort_t* ldsb[3];
#pragma unroll
  for (int bp = 0; bp < 3; ++bp)
    ldsb[bp] = LDS + 16384 + bp*16384 + wv*4096;

  auto ISSUE = [&](int c, int bp){
    const int ko = (c - 4)*64;
    if (wv < 2){
#pragma unroll
      for (int j = 0; j < 8; ++j) stage16(pj[j] + ko, ldsb[bp] + j*512);
    } else {
#pragma unroll
      for (int j = 0; j < 8; ++j) stage16c(pj[j] + ko, ldsb[bp] + j*512);
    }
  };

  f32x4 acc[2][2] = {};
  auto rdf = [&](const ushort_t* buf, int ks, Frags& f){
    const int ga = (((ks << 2) + cb) ^ sx) << 3;
    f.awh0 = *(const bfx8*)(buf +         rwa0*64 + ga);
    f.awh1 = *(const bfx8*)(buf +         rwa1*64 + ga);
    f.awl0 = *(const bfx8*)(buf + 4096  + rwa0*64 + ga);
    f.awl1 = *(const bfx8*)(buf + 4096  + rwa1*64 + ga);
    f.bh0  = *(const bfx8*)(buf + 8192  + rwb0*64 + ga);
    f.bh1  = *(const bfx8*)(buf + 8192  + rwb1*64 + ga);
    f.bl0  = *(const bfx8*)(buf + 12288 + rwb0*64 + ga);
    f.bl1  = *(const bfx8*)(buf + 12288 + rwb1*64 + ga);
  };
  auto mm12 = [&](const Frags& f){
    acc[0][0] = MFMA(f.awh0, f.bh0, acc[0][0]);
    acc[0][0] = MFMA(f.awh0, f.bl0, acc[0][0]);
    acc[0][0] = MFMA(f.awl0, f.bh0, acc[0][0]);
    acc[0][1] = MFMA(f.awh0, f.bh1, acc[0][1]);
    acc[0][1] = MFMA(f.awh0, f.bl1, acc[0][1]);
    acc[0][1] = MFMA(f.awl0, f.bh1, acc[0][1]);
    acc[1][0] = MFMA(f.awh1, f.bh0, acc[1][0]);
    acc[1][0] = MFMA(f.awh1, f.bl0, acc[1][0]);
    acc[1][0] = MFMA(f.awl1, f.bh0, acc[1][0]);
    acc[1][1] = MFMA(f.awh1, f.bh1, acc[1][1]);
    acc[1][1] = MFMA(f.awh1, f.bl1, acc[1][1]);
    acc[1][1] = MFMA(f.awl1, f.bh1, acc[1][1]);
  };

  f32x4 rw0a, rw0b, rw1a, rw1b;
  bfx8 cwh0, cwh1, cwl0, cwl1, cah0, cah1, cal0, cal1;
  auto LOADRAW = [&](int kc){
    rw0a = *(const f32x4*)(wih0 + kc);  rw0b = *(const f32x4*)(wih0 + kc + 4);
    rw1a = *(const f32x4*)(wih1 + kc);  rw1b = *(const f32x4*)(wih1 + kc + 4);
    cah0 = ld16c(ih0 + kc);  cah1 = ld16c(ih1 + kc);
    cal0 = ld16c(il0 + kc);  cal1 = ld16c(il1 + kc);
  };
  auto CVT = [&](){
    cvt2(rw0a, rw0b, cwh0, cwl0);
    cvt2(rw1a, rw1b, cwh1, cwl1);
  };

  LOADRAW(0);
  ISSUE(4, 0); ISSUE(5, 1); ISSUE(6, 2);
  CVT();

  for (int c = 0; c < 4; ++c){
    *(bfx8*)(LDS +         lr    *64 + lc*8) = cwh0;
    *(bfx8*)(LDS +        (lr+32)*64 + lc*8) = cwh1;
    *(bfx8*)(LDS + 4096 +  lr    *64 + lc*8) = cwl0;
    *(bfx8*)(LDS + 4096 + (lr+32)*64 + lc*8) = cwl1;
    *(bfx8*)(LDS + 8192 +  lr    *64 + lc*8) = cah0;
    *(bfx8*)(LDS + 8192 + (lr+32)*64 + lc*8) = cah1;
    *(bfx8*)(LDS + 12288 + lr    *64 + lc*8) = cal0;
    *(bfx8*)(LDS + 12288 +(lr+32)*64 + lc*8) = cal1;
    WAITLG(0); SBAR();
    if (c < 3) LOADRAW((c + 1)*64);
    Frags f0, f1;
    rdf(LDS, 0, f0);
    rdf(LDS, 1, f1);
    WAITLG(8);
    mm12(f0);
    WAITLG(0); SBAR();
    if (c < 3) CVT();
    mm12(f1);
  }

  int bi = 0;
  for (int i = 4; i <= 19; ++i){
    if (i < 18)      { WAITVM(16); }
    else if (i == 18){ WAITVM(8); }
    else             { WAITVM(0); }
    SBAR();
    const ushort_t* buf = LDS + 16384 + bi*16384;
    Frags f0, f1;
    rdf(buf, 0, f0);
    rdf(buf, 1, f1);
    WAITLG(8);
    mm12(f0);
    WAITLG(0); SBAR();
    if (i <= 16) ISSUE(i + 3, bi);
    mm12(f1);
    bi = (bi == 2) ? 0 : bi + 1;
  }

#pragma unroll
  for (int m = 0; m < 2; ++m){
    const int n = n0 + wm*8 + m*4 + cb;
    const float bi_ = bias[n];
    const float bf_ = bias[1024 + n];
    const float bg_ = bias[2048 + n];
    const float bo_ = bias[3072 + n];
#pragma unroll
    for (int nb = 0; nb < 2; ++nb){
      const int b = b0 + wn*32 + nb*16 + fr;
      float gi = acc[m][nb][0] + bi_;
      float gf = acc[m][nb][1] + bf_;
      float gg = acc[m][nb][2] + bg_;
      float go = acc[m][nb][3] + bo_;
      float c_new = sigm(gf)*creg[m][nb] + sigm(gi)*tanh_(gg);
      float h_new = sigm(go)*tanh_(c_new);
      creg[m][nb] = c_new;
      unsigned short hi = f2bf(h_new);
      sth2(&outh[(size_t)b*2048 + n], hi);
      sth2(&outl[(size_t)b*2048 + n], f2bf(h_new - bf2f(hi)));
    }
  }
}

// ---------------------------------------------------------------------------
// Decoder MLP (R7): 256 WGs = 16 d-tiles x 8 b-tiles x 2 K-halves; wave K=256
// strip, wave-private LDS staging; partials coherent to Part.
// ---------------------------------------------------------------------------
__device__ __forceinline__ void mlp_gemm(
    const ushort_t* __restrict__ hch, const ushort_t* __restrict__ hcl,
    const ushort_t* __restrict__ mWh, const ushort_t* __restrict__ mWl,
    float* __restrict__ Part, int wg, ushort_t* LDS)
{
  const int tid = threadIdx.x, lane = tid & 63, wv = tid >> 6;
  const int cb = lane >> 4, fr = lane & 15, sx = fr & 7;
  const int wgl = wg & 127, kh = wg >> 7;
  const int d0 = (wgl >> 3)*16, b0 = (wgl & 7)*16;
  const int kb = kh*1024 + wv*256;
  const int srw = lane >> 3, sg = (lane & 7) ^ srw;

  const ushort_t* ps[4] = { mWh, mWl, hch, hcl };
  const int pr0[4] = { d0, d0, b0, b0 };
  const ushort_t* pj[4][2];
#pragma unroll
  for (int p = 0; p < 4; ++p)
#pragma unroll
    for (int j = 0; j < 2; ++j)
      pj[p][j] = ps[p] + (size_t)(pr0[p] + j*8 + srw)*2048 + kb + sg*8;
  ushort_t* lb[3];
#pragma unroll
  for (int bp = 0; bp < 3; ++bp)
    lb[bp] = LDS + 16384 + (wv*3 + bp)*4096;

  auto ISSUE = [&](int c, int bp){
    const int ko = c*64;
#pragma unroll
    for (int p = 0; p < 4; ++p)
#pragma unroll
      for (int j = 0; j < 2; ++j){
        if (p < 2) stage16 (pj[p][j] + ko, lb[bp] + p*1024 + j*512);
        else       stage16c(pj[p][j] + ko, lb[bp] + p*1024 + j*512);
      }
  };
  ISSUE(0, 0); ISSUE(1, 1); ISSUE(2, 2);

  f32x4 acc = {};
  int bp = 0;
  for (int c = 0; c < 4; ++c){
    if (c < 2)      { WAITVM(16); }
    else if (c == 2){ WAITVM(8); }
    else            { WAITVM(0); }
    const ushort_t* B = lb[bp];
    const int ga0 = ((cb) ^ sx) << 3;
    const int ga1 = ((4 + cb) ^ sx) << 3;
    bfx8 wh0 = *(const bfx8*)(B +        fr*64 + ga0);
    bfx8 wl0 = *(const bfx8*)(B + 1024 + fr*64 + ga0);
    bfx8 ah0 = *(const bfx8*)(B + 2048 + fr*64 + ga0);
    bfx8 al0 = *(const bfx8*)(B + 3072 + fr*64 + ga0);
    bfx8 wh1 = *(const bfx8*)(B +        fr*64 + ga1);
    bfx8 wl1 = *(const bfx8*)(B + 1024 + fr*64 + ga1);
    bfx8 ah1 = *(const bfx8*)(B + 2048 + fr*64 + ga1);
    bfx8 al1 = *(const bfx8*)(B + 3072 + fr*64 + ga1);
    WAITLG(0);
    if (c == 0) ISSUE(3, 0);
    acc = MFMA(wh0, ah0, acc); acc = MFMA(wh0, al0, acc); acc = MFMA(wl0, ah0, acc);
    acc = MFMA(wh1, ah1, acc); acc = MFMA(wh1, al1, acc); acc = MFMA(wl1, ah1, acc);
    bp = (bp == 2) ? 0 : bp + 1;
  }
  u64* P8 = (u64*)Part;
  const size_t idx = (((size_t)wgl*2 + kh)*4 + wv)*64 + lane;
  u64 a = ((u64)__float_as_uint(acc[1]) << 32) | __float_as_uint(acc[0]);
  u64 b = ((u64)__float_as_uint(acc[3]) << 32) | __float_as_uint(acc[2]);
  __hip_atomic_store(&P8[2*idx],     a, __ATOMIC_RELAXED, __HIP_MEMORY_SCOPE_AGENT);
  __hip_atomic_store(&P8[2*idx + 1], b, __ATOMIC_RELAXED, __HIP_MEMORY_SCOPE_AGENT);
}

__device__ __forceinline__ void mlp_combine(
    const float* __restrict__ Part, const float* __restrict__ mb,
    float* __restrict__ dout,
    ushort_t* __restrict__ inph, ushort_t* __restrict__ inpl, int wg, int t)
{
  if (threadIdx.x >= 64) return;
  const int lane = threadIdx.x;
  const int d0 = (wg >> 3)*16, b0 = (wg & 7)*16;
  const int cb = lane >> 4, fr = lane & 15;
  const u64* P8 = (const u64*)Part;
  f32x4 s = {};
#pragma unroll
  for (int kh = 0; kh < 2; ++kh)
#pragma unroll
    for (int wv = 0; wv < 4; ++wv){
      const size_t idx = (((size_t)wg*2 + kh)*4 + wv)*64 + lane;
      u64 a = __hip_atomic_load(&P8[2*idx],     __ATOMIC_RELAXED, __HIP_MEMORY_SCOPE_AGENT);
      u64 b = __hip_atomic_load(&P8[2*idx + 1], __ATOMIC_RELAXED, __HIP_MEMORY_SCOPE_AGENT);
      s[0] += __uint_as_float((unsigned)a);
      s[1] += __uint_as_float((unsigned)(a >> 32));
      s[2] += __uint_as_float((unsigned)b);
      s[3] += __uint_as_float((unsigned)(b >> 32));
    }
  const int dr = d0 + cb*4, b = b0 + fr;
  s += *(const f32x4*)&mb[dr];
  *(f32x4*)&dout[((size_t)b*128 + t)*256 + dr] = s;
  u16x4 hv, lv;
#pragma unroll
  for (int j = 0; j < 4; ++j){
    hv[j] = f2bf(s[j]);
    lv[j] = f2bf(s[j] - bf2f(hv[j]));
  }
  union { u16x4 v; u64 u; } ch, cl; ch.v = hv; cl.v = lv;
  __hip_atomic_store((u64*)&inph[(size_t)b*256 + dr], ch.u, __ATOMIC_RELAXED, __HIP_MEMORY_SCOPE_AGENT);
  __hip_atomic_store((u64*)&inpl[(size_t)b*256 + dr], cl.u, __ATOMIC_RELAXED, __HIP_MEMORY_SCOPE_AGENT);
}

// WG -> (dir, rowgroup, b-half); b-halves 8 apart => XCD co-location.
__device__ __forceinline__ void wg_decode(int wg, int& dir, int& r0, int& n0,
                                          int& b0, int& me){
  const int half = (wg >> 3) & 1;
  const int rgd  = (wg & 7) | ((wg >> 4) << 3);        // 0..127
  dir = rgd >> 6;
  const int rg = rgd & 63;
  r0 = rg * 64; n0 = rg * 16; b0 = half * 64;
  me = (rg << 1) | half;                               // 0..127 within dir
}

// Build the encoder W-prefetch descriptor (chunks 4,5 into W slots 0,1).
__device__ __forceinline__ WPre make_wpre(const ushort_t* WhH, const ushort_t* WhL,
                                          int r0, ushort_t* LDS){
  const int tid = threadIdx.x, lane = tid & 63, wv = tid >> 6;
  const int srw = lane >> 3;
  const int sg  = (lane & 7) ^ srw;
  WPre w;
  w.active = (wv < 2);
  const ushort_t* sb = (wv == 1) ? WhL : WhH;
#pragma unroll
  for (int j = 0; j < 8; ++j)
    w.pj[j] = sb + (size_t)(r0 + j*8 + srw)*1024 + sg*8;
#pragma unroll
  for (int s = 0; s < 2; ++s)
    w.ldsb[s] = LDS + 16384 + s*8192 + (wv & 1)*4096;
  return w;
}

__global__ void __launch_bounds__(256) rnn_enc_kernel(
    const float* __restrict__ Wih_f, const float* __restrict__ b_f,
    const float* __restrict__ Wih_b, const float* __restrict__ b_b,
    const ushort_t* __restrict__ WhhH, const ushort_t* __restrict__ WhhL,
    const float* __restrict__ x,
    ushort_t* __restrict__ Hh, ushort_t* __restrict__ Hl,
    float* __restrict__ C, unsigned* flagsE)
{
  extern __shared__ ushort_t LDS[];
  int dir, r0, n0, b0, me;
  wg_decode(blockIdx.x, dir, r0, n0, b0, me);
  const float* Wih = dir ? Wih_b : Wih_f;
  const float* bia = dir ? b_b : b_f;
  const ushort_t* WhH = WhhH + (size_t)dir*4096*1024;
  const ushort_t* WhL = WhhL + (size_t)dir*4096*1024;
  unsigned* fl = flagsE + dir*128;
  const WPre wp = make_wpre(WhH, WhL, r0, LDS);

  float creg[2][2] = {{0.f, 0.f}, {0.f, 0.f}};
  wpre_issue(wp);                           // t=0 W prologue
  for (int t = 0; t < 256; ++t){
    const int tt = dir ? (255 - t) : t;
    const int rp = t & 1;
    cell_enc(Wih, WhH, WhL, bia,
             x + (size_t)tt*256,
             Hh + (size_t)rp     *262144 + dir*1024,
             Hl + (size_t)rp     *262144 + dir*1024,
             Hh + (size_t)(rp^1) *262144 + dir*1024,
             Hl + (size_t)(rp^1) *262144 + dir*1024,
             creg, r0, n0, b0, LDS);
    bar_pf(fl, 128, me, (unsigned)(t + 1), wp, t < 255);
  }
  // hand off c-state to decoder (cross-kernel boundary flushes)
  {
    const int lane = threadIdx.x & 63, wv = threadIdx.x >> 6;
    const int wm = wv >> 1, wn = wv & 1, cb = lane >> 4, fr = lane & 15;
    float* Cst = C + (size_t)dir*1024*128;
#pragma unroll
    for (int m = 0; m < 2; ++m)
#pragma unroll
      for (int nb = 0; nb < 2; ++nb){
        const int n = n0 + wm*8 + m*4 + cb;
        const int b = b0 + wn*32 + nb*16 + fr;
        Cst[n*128 + b] = creg[m][nb];
      }
  }
}

__global__ void __launch_bounds__(256) rnn_dec_kernel(
    const float* __restrict__ Wih_f, const float* __restrict__ b_f,
    const float* __restrict__ Wih_b, const float* __restrict__ b_b,
    const ushort_t* __restrict__ WhhH, const ushort_t* __restrict__ WhhL,
    const ushort_t* __restrict__ mWh, const ushort_t* __restrict__ mWl,
    const float* __restrict__ mb,
    ushort_t* __restrict__ Hh, ushort_t* __restrict__ Hl,
    float* __restrict__ C,
    ushort_t* __restrict__ inph, ushort_t* __restrict__ inpl,
    float* __restrict__ Part,
    float* __restrict__ dout, unsigned* flagsD)
{
  extern __shared__ ushort_t LDS[];
  const int wg = blockIdx.x;
  int dir, r0, n0, b0, me;
  wg_decode(wg, dir, r0, n0, b0, me);
  const float* Wih = dir ? Wih_b : Wih_f;
  const float* bia = dir ? b_b : b_f;
  const ushort_t* WhH = WhhH + (size_t)dir*4096*1024;
  const ushort_t* WhL = WhhL + (size_t)dir*4096*1024;
  float creg[2][2];
  {
    const int lane = threadIdx.x & 63, wv = threadIdx.x >> 6;
    const int wm = wv >> 1, wn = wv & 1, cb = lane >> 4, fr = lane & 15;
    const float* Cst = C + (size_t)dir*1024*128;
#pragma unroll
    for (int m = 0; m < 2; ++m)
#pragma unroll
      for (int nb = 0; nb < 2; ++nb){
        const int n = n0 + wm*8 + m*4 + cb;
        const int b = b0 + wn*32 + nb*16 + fr;
        creg[m][nb] = Cst[n*128 + b];
      }
  }
  for (int t = 0; t < 128; ++t){
    const int rp = t & 1;
    cell_dec(Wih, WhH, WhL, bia,
             inph, inpl,
             Hh + (size_t)rp     *262144 + dir*1024,
             Hl + (size_t)rp     *262144 + dir*1024,
             Hh + (size_t)(rp^1) *262144 + dir*1024,
             Hl + (size_t)(rp^1) *262144 + dir*1024,
             creg, r0, n0, b0, LDS);
    bar(flagsD, 256, wg, (unsigned)(3*t + 1));
    mlp_gemm(Hh + (size_t)(rp^1)*262144, Hl + (size_t)(rp^1)*262144,
             mWh, mWl, Part, wg, LDS);
    bar(flagsD, 256, wg, (unsigned)(3*t + 2));
    if (wg < 128) mlp_combine(Part, mb, dout, inph, inpl, wg, t);
    bar(flagsD, 256, wg, (unsigned)(3*t + 3));
  }
}

// ---------------------------------------------------------------------------
// Prep kernels
// ---------------------------------------------------------------------------
__global__ void k_wplanes(ushort_t* Hp, ushort_t* Lp,
                          const float* Whh_f, const float* Whh_b)
{
  const size_t N = 2ull*4096*1024;
  for (size_t i = (size_t)blockIdx.x*blockDim.x + threadIdx.x; i < N;
       i += (size_t)gridDim.x*blockDim.x){
    int dir = (int)(i >> 22);
    int r   = (int)((i >> 10) & 4095);
    int k   = (int)(i & 1023);
    int n = r >> 2, q = r & 3;
    const float* W = dir ? Whh_b : Whh_f;
    float v = W[(size_t)(q*1024 + n)*1024 + k];
    unsigned short h = f2bf(v);
    Hp[i] = h;
    Lp[i] = f2bf(v - bf2f(h));
  }
}

__global__ void k_init(ushort_t* Hh, ushort_t* Hl,
                       ushort_t* inph, ushort_t* inpl,
                       ushort_t* mWh, ushort_t* mWl,
                       const float* x, const float* mW, unsigned* cnt)
{
  const size_t N = 524288;
  for (size_t i = (size_t)blockIdx.x*blockDim.x + threadIdx.x; i < N;
       i += (size_t)gridDim.x*blockDim.x){
    Hh[i] = 0; Hl[i] = 0;
    float wv = mW[i];
    unsigned short wh = f2bf(wv);
    mWh[i] = wh;
    mWl[i] = f2bf(wv - bf2f(wh));
    if (i < 32768){
      int b = (int)(i >> 8), d = (int)(i & 255);
      float v = x[((size_t)b*256 + 255)*256 + d];        // x[:, 255, :]
      unsigned short hi = f2bf(v);
      inph[i] = hi;
      inpl[i] = f2bf(v - bf2f(hi));
    }
    if (i < 2048) cnt[i] = 0;
  }
}

// ---------------------------------------------------------------------------
extern "C" void kernel_launch(void* const* d_in, const int* in_sizes, int n_in,
                              void* d_out, int out_size, void* d_ws, size_t ws_size,
                              hipStream_t stream)
{
  (void)in_sizes; (void)n_in; (void)out_size; (void)ws_size;
  const float* x      = (const float*)d_in[0];
  const float* eWih_f = (const float*)d_in[2];
  const float* eWhh_f = (const float*)d_in[3];
  const float* eb_f   = (const float*)d_in[4];
  const float* eWih_b = (const float*)d_in[5];
  const float* eWhh_b = (const float*)d_in[6];
  const float* eb_b   = (const float*)d_in[7];
  const float* dWih_f = (const float*)d_in[8];
  const float* dWhh_f = (const float*)d_in[9];
  const float* db_f   = (const float*)d_in[10];
  const float* dWih_b = (const float*)d_in[11];
  const float* dWhh_b = (const float*)d_in[12];
  const float* db_b   = (const float*)d_in[13];
  const float* mW     = (const float*)d_in[14];
  const float* mb     = (const float*)d_in[15];

  char* p = (char*)d_ws;
  size_t off = 0;
  unsigned* cnt   = (unsigned*)(p + off);  off += 8192;
  ushort_t* WhhEh = (ushort_t*)(p + off);  off += 16777216;
  ushort_t* WhhEl = (ushort_t*)(p + off);  off += 16777216;
  ushort_t* WhhDh = (ushort_t*)(p + off);  off += 16777216;
  ushort_t* WhhDl = (ushort_t*)(p + off);  off += 16777216;
  ushort_t* mWh   = (ushort_t*)(p + off);  off += 1048576;
  ushort_t* mWl   = (ushort_t*)(p + off);  off += 1048576;
  ushort_t* Hh    = (ushort_t*)(p + off);  off += 1048576;
  ushort_t* Hl    = (ushort_t*)(p + off);  off += 1048576;
  float*    C     = (float*)(p + off);     off += 1048576;
  ushort_t* inph  = (ushort_t*)(p + off);  off += 65536;
  ushort_t* inpl  = (ushort_t*)(p + off);  off += 65536;
  float*    Part  = (float*)(p + off);     off += 1048576;

  unsigned* flagsD = cnt;              // 256
  unsigned* flagsE = cnt + 256;        // 2 x 128

  hipFuncSetAttribute(reinterpret_cast<const void*>(rnn_enc_kernel),
                      hipFuncAttributeMaxDynamicSharedMemorySize, 147456);
  hipFuncSetAttribute(reinterpret_cast<const void*>(rnn_dec_kernel),
                      hipFuncAttributeMaxDynamicSharedMemorySize, 131072);

  k_init   <<<512, 256, 0, stream>>>(Hh, Hl, inph, inpl, mWh, mWl, x, mW, cnt);
  k_wplanes<<<2048, 256, 0, stream>>>(WhhEh, WhhEl, eWhh_f, eWhh_b);
  k_wplanes<<<2048, 256, 0, stream>>>(WhhDh, WhhDl, dWhh_f, dWhh_b);

  rnn_enc_kernel<<<NWG, 256, 147456, stream>>>(eWih_f, eb_f, eWih_b, eb_b,
                                               WhhEh, WhhEl, x, Hh, Hl, C, flagsE);
  rnn_dec_kernel<<<NWG, 256, 131072, stream>>>(dWih_f, db_f, dWih_b, db_b,
                                               WhhDh, WhhDl, mWh, mWl, mb,
                                               Hh, Hl, C, inph, inpl, Part,
                                               (float*)d_out, flagsD);
}